// Round 2
// baseline (1260.005 us; speedup 1.0000x reference)
//
#include <hip/hip_runtime.h>
#include <hip/hip_bf16.h>

#define DD 2048
#define TT 2048
#define NHEAD 16
#define HDIM 128
#define QKVN 6144

typedef __attribute__((ext_vector_type(8))) short short8;
typedef __attribute__((ext_vector_type(4))) float f32x4;

__device__ __forceinline__ short f2bf(float f) {
  __hip_bfloat16 h = __float2bfloat16(f);
  return *reinterpret_cast<short*>(&h);
}

__device__ __forceinline__ f32x4 mfma_bf16(short8 a, short8 b, f32x4 c) {
  return __builtin_amdgcn_mfma_f32_16x16x32_bf16(a, b, c, 0, 0, 0);
}

__device__ __forceinline__ float gelu_exact(float v) {
  return 0.5f * v * (1.0f + erff(v * 0.70710678118654752440f));
}

// ---------------- fp32 -> bf16 convert (n multiple of 2048) ----------------
__global__ __launch_bounds__(256) void cvt_bf16_kernel(const float* __restrict__ in,
                                                       short* __restrict__ outp) {
  const size_t i = ((size_t)blockIdx.x * 256 + threadIdx.x) * 8;
  const f32x4 a = *(const f32x4*)&in[i];
  const f32x4 b = *(const f32x4*)&in[i + 4];
  short8 o;
#pragma unroll
  for (int e = 0; e < 4; ++e) { o[e] = f2bf(a[e]); o[e + 4] = f2bf(b[e]); }
  *(short8*)&outp[i] = o;
}

// ---------------- mean over T, partial sums: part[(b*8+tc)*D + d] ----------------
__global__ __launch_bounds__(256) void mean_partial_kernel(const float* __restrict__ x,
                                                           float* __restrict__ part) {
  const int d = blockIdx.x * 256 + threadIdx.x;
  const int y = blockIdx.y;             // b*8 + tchunk
  const int b = y >> 3, tc = y & 7;
  const float* p = x + (size_t)b * TT * DD + (size_t)tc * 256 * DD + d;
  float s = 0.f;
#pragma unroll 4
  for (int t = 0; t < 256; ++t) s += p[(size_t)t * DD];
  part[(size_t)y * DD + d] = s;
}

// ---------------- gates: g[b*8+m] = sigmoid(x_state . gate_w[16+m] + gate_b[16+m]) ----------------
__global__ __launch_bounds__(256) void gates_kernel(const float* __restrict__ part,
                                                    const float* __restrict__ gw,
                                                    const float* __restrict__ gb,
                                                    float* __restrict__ g) {
  const int bm = blockIdx.x;            // b*8 + m
  const int b = bm >> 3, mm = bm & 7;
  const int j = 16 + mm;
  float acc = 0.f;
  for (int d = threadIdx.x; d < DD; d += 256) {
    float xv = 0.f;
#pragma unroll
    for (int tc = 0; tc < 8; ++tc) xv += part[(size_t)(b * 8 + tc) * DD + d];
    acc += xv * (1.f / TT) * gw[(size_t)j * DD + d];
  }
#pragma unroll
  for (int d = 1; d < 64; d <<= 1) acc += __shfl_xor(acc, d);
  __shared__ float ws4[4];
  if ((threadIdx.x & 63) == 0) ws4[threadIdx.x >> 6] = acc;
  __syncthreads();
  if (threadIdx.x == 0) {
    const float tot = ws4[0] + ws4[1] + ws4[2] + ws4[3] + gb[j];
    g[bm] = 1.f / (1.f + __expf(-tot));
  }
}

// ---------------- Sinkhorn-Knopp, 8x8, 15 iters, one 64-thread block ----------------
__global__ void sinkhorn_kernel(const float* __restrict__ phi, float* __restrict__ H) {
  __shared__ float M[64];
  const int t = threadIdx.x;
  const int i = t >> 3, j = t & 7;
  M[t] = __expf(phi[t]);
  __syncthreads();
  for (int it = 0; it < 15; ++it) {
    float rs = 0.f;
#pragma unroll
    for (int jj = 0; jj < 8; ++jj) rs += M[i * 8 + jj];
    float v = M[t] / rs;
    __syncthreads(); M[t] = v; __syncthreads();
    float cs = 0.f;
#pragma unroll
    for (int ii = 0; ii < 8; ++ii) cs += M[ii * 8 + j];
    v = M[t] / cs;
    __syncthreads(); M[t] = v; __syncthreads();
  }
  H[t] = M[t];
}

// ---------------- RMSNorm fp32 -> bf16, one block per row ----------------
__global__ __launch_bounds__(256) void rmsnorm_kernel(const float* __restrict__ x,
                                                      const float* __restrict__ wt,
                                                      short* __restrict__ outp) {
  const int row = blockIdx.x;
  const int tid = threadIdx.x;
  const float* xr = x + (size_t)row * DD;
  const f32x4 v0 = *(const f32x4*)&xr[tid * 8];
  const f32x4 v1 = *(const f32x4*)&xr[tid * 8 + 4];
  float ss = 0.f;
#pragma unroll
  for (int e = 0; e < 4; ++e) ss += v0[e] * v0[e] + v1[e] * v1[e];
#pragma unroll
  for (int d = 1; d < 64; d <<= 1) ss += __shfl_xor(ss, d);
  __shared__ float wsum[4];
  if ((tid & 63) == 0) wsum[tid >> 6] = ss;
  __syncthreads();
  const float rstd = rsqrtf((wsum[0] + wsum[1] + wsum[2] + wsum[3]) * (1.f / DD) + 1e-6f);
  const f32x4 w0 = *(const f32x4*)&wt[tid * 8];
  const f32x4 w1 = *(const f32x4*)&wt[tid * 8 + 4];
  short8 ov;
#pragma unroll
  for (int e = 0; e < 4; ++e) {
    ov[e] = f2bf(v0[e] * rstd * w0[e]);
    ov[e + 4] = f2bf(v1[e] * rstd * w1[e]);
  }
  *(short8*)&outp[(size_t)row * DD + tid * 8] = ov;
}

// ---------------- NT bf16 GEMM: C[M,N] = A[M,K] * B[N,K]^T + bias (+epilogue) ----------------
// EPI: 0 = fp32 out; 1 = GELU -> bf16; 2 = +resid -> fp32; 3 = bf16 out
template <int EPI>
__global__ __launch_bounds__(256) void gemm_nt(const short* __restrict__ A,
                                               const short* __restrict__ B,
                                               const float* __restrict__ bias,
                                               void* __restrict__ Cptr,
                                               const float* __restrict__ resid,
                                               int M, int N, int K) {
  __shared__ __align__(16) short As[128 * 64];
  __shared__ __align__(16) short Bs[128 * 64];
  const int tid = threadIdx.x;
  const int lane = tid & 63;
  const int wid = tid >> 6;
  const int bm = blockIdx.x * 128;
  const int bn = blockIdx.y * 128;
  const int wr = (wid >> 1) * 64;
  const int wc = (wid & 1) * 64;
  f32x4 acc[4][4] = {};

  for (int kb = 0; kb < K; kb += 64) {
    __syncthreads();
#pragma unroll
    for (int p = 0; p < 4; ++p) {
      const int flat = p * 2048 + tid * 8;
      const int row = flat >> 6;
      const int col = flat & 63;
      // XOR-swizzle the 16B chunk index with row&7 (write side; read side matches)
      const int dst = (row << 6) | (((col >> 3) ^ (row & 7)) << 3);
      *(int4*)&As[dst] = *(const int4*)&A[(size_t)(bm + row) * K + kb + col];
      *(int4*)&Bs[dst] = *(const int4*)&B[(size_t)(bn + row) * K + kb + col];
    }
    __syncthreads();
#pragma unroll
    for (int kk = 0; kk < 64; kk += 32) {
      short8 af[4], bfr[4];
#pragma unroll
      for (int i = 0; i < 4; ++i) {
        const int row = wr + i * 16 + (lane & 15);
        const int ch = ((kk >> 3) + (lane >> 4)) ^ (row & 7);
        af[i] = *(const short8*)&As[(row << 6) | (ch << 3)];
      }
#pragma unroll
      for (int j = 0; j < 4; ++j) {
        const int row = wc + j * 16 + (lane & 15);
        const int ch = ((kk >> 3) + (lane >> 4)) ^ (row & 7);
        bfr[j] = *(const short8*)&Bs[(row << 6) | (ch << 3)];
      }
#pragma unroll
      for (int i = 0; i < 4; ++i)
#pragma unroll
        for (int j = 0; j < 4; ++j)
          acc[i][j] = mfma_bf16(af[i], bfr[j], acc[i][j]);
    }
  }

  const int r0 = bm + wr + (lane >> 4) * 4;
  const int c0 = bn + wc + (lane & 15);
#pragma unroll
  for (int i = 0; i < 4; ++i) {
#pragma unroll
    for (int j = 0; j < 4; ++j) {
      const int col = c0 + j * 16;
      const float bv = bias[col];
#pragma unroll
      for (int r = 0; r < 4; ++r) {
        const int row = r0 + i * 16 + r;
        const float v = acc[i][j][r] + bv;
        if constexpr (EPI == 0) {
          ((float*)Cptr)[(size_t)row * N + col] = v;
        } else if constexpr (EPI == 1) {
          ((short*)Cptr)[(size_t)row * N + col] = f2bf(gelu_exact(v));
        } else if constexpr (EPI == 2) {
          ((float*)Cptr)[(size_t)row * N + col] = v + resid[(size_t)row * N + col];
        } else {
          ((short*)Cptr)[(size_t)row * N + col] = f2bf(v);
        }
      }
    }
  }
}

// ---------------- causal flash attention: qkv bf16 [B*T, 6144] -> attn bf16 [B*T, 2048] ----------------
__global__ __launch_bounds__(256) void flash_attn_kernel(const short* __restrict__ qkv,
                                                         short* __restrict__ attn) {
  const int tid = threadIdx.x;
  const int lane = tid & 63;
  const int w = tid >> 6;
  const int qb = blockIdx.x * 64;
  const int h = blockIdx.y;
  const int b = blockIdx.z;

  __shared__ __align__(16) short Ks[32 * 128];   // [kv][d], chunk-swizzled
  __shared__ __align__(16) short Vt[128 * 40];   // [d][kv], pad 40 (16B-aligned rows)
  __shared__ __align__(16) short Ps[4][512];     // per-wave P in A-frag layout [chunk][row][8]

  const size_t base = (size_t)b * TT * QKVN;
  const int lr = lane & 15;
  const int lg = lane >> 4;

  const int qrow = qb + w * 16 + lr;
  short8 qf[4];
#pragma unroll
  for (int c = 0; c < 4; ++c)
    qf[c] = *(const short8*)&qkv[base + (size_t)qrow * QKVN + h * HDIM + c * 32 + lg * 8];

  f32x4 o[8] = {};
  float mrow[4] = {-1e30f, -1e30f, -1e30f, -1e30f};
  float lrow[4] = {0.f, 0.f, 0.f, 0.f};

  const int ntiles = (qb >> 5) + 2;
  for (int t = 0; t < ntiles; ++t) {
    const int kv0 = t * 32;
    __syncthreads();
#pragma unroll
    for (int p = 0; p < 2; ++p) {
      const int flat = p * 2048 + tid * 8;
      const int r = flat >> 7;
      const int c = flat & 127;
      const int dst = (r << 7) | (((c >> 3) ^ (r & 7)) << 3);
      *(int4*)&Ks[dst] = *(const int4*)&qkv[base + (size_t)(kv0 + r) * QKVN + 2048 + h * HDIM + c];
      const short8 vv = *(const short8*)&qkv[base + (size_t)(kv0 + r) * QKVN + 4096 + h * HDIM + c];
#pragma unroll
      for (int e = 0; e < 8; ++e) Vt[(c + e) * 40 + r] = vv[e];
    }
    __syncthreads();

    f32x4 s0 = {}, s1 = {};
#pragma unroll
    for (int c = 0; c < 4; ++c) {
      const int ch = c * 4 + lg;
      const short8 b0 = *(const short8*)&Ks[(lr << 7) | ((ch ^ (lr & 7)) << 3)];
      const short8 b1 = *(const short8*)&Ks[((lr + 16) << 7) | ((ch ^ (lr & 7)) << 3)];
      s0 = mfma_bf16(qf[c], b0, s0);
      s1 = mfma_bf16(qf[c], b1, s1);
    }

    const float sc = 0.08838834764831845f;  // 1/sqrt(128)
    const int qr0 = qb + w * 16 + lg * 4;
    const int cc = kv0 + lr;
    float sv0[4], sv1[4], pm[4];
#pragma unroll
    for (int r = 0; r < 4; ++r) {
      sv0[r] = (cc <= qr0 + r) ? s0[r] * sc : -1e30f;
      sv1[r] = (cc + 16 <= qr0 + r) ? s1[r] * sc : -1e30f;
      pm[r] = fmaxf(sv0[r], sv1[r]);
    }
#pragma unroll
    for (int d = 1; d < 16; d <<= 1) {
#pragma unroll
      for (int r = 0; r < 4; ++r) pm[r] = fmaxf(pm[r], __shfl_xor(pm[r], d));
    }
    float p0[4], p1[4], rs[4];
#pragma unroll
    for (int r = 0; r < 4; ++r) {
      const float mn = fmaxf(mrow[r], pm[r]);
      const float al = __expf(mrow[r] - mn);
      mrow[r] = mn;
      p0[r] = __expf(sv0[r] - mn);
      p1[r] = __expf(sv1[r] - mn);
      rs[r] = p0[r] + p1[r];
      lrow[r] *= al;
#pragma unroll
      for (int ch = 0; ch < 8; ++ch) o[ch][r] *= al;
    }
#pragma unroll
    for (int d = 1; d < 16; d <<= 1) {
#pragma unroll
      for (int r = 0; r < 4; ++r) rs[r] += __shfl_xor(rs[r], d);
    }
#pragma unroll
    for (int r = 0; r < 4; ++r) lrow[r] += rs[r];

#pragma unroll
    for (int r = 0; r < 4; ++r) {
      const int rowp = lg * 4 + r;
      Ps[w][((lr >> 3) << 7) | (rowp << 3) | (lr & 7)] = f2bf(p0[r]);
      Ps[w][(((lr + 16) >> 3) << 7) | (rowp << 3) | (lr & 7)] = f2bf(p1[r]);
    }
    const short8 pf = *(const short8*)&Ps[w][(lg << 7) | (lr << 3)];
#pragma unroll
    for (int ch = 0; ch < 8; ++ch) {
      const short8 vf = *(const short8*)&Vt[(ch * 16 + lr) * 40 + lg * 8];
      o[ch] = mfma_bf16(pf, vf, o[ch]);
    }
  }

#pragma unroll
  for (int ch = 0; ch < 8; ++ch) {
#pragma unroll
    for (int r = 0; r < 4; ++r) {
      const int row = qb + w * 16 + lg * 4 + r;
      const int col = h * HDIM + ch * 16 + lr;
      attn[((size_t)b * TT + row) * DD + col] = f2bf(o[ch][r] / lrow[r]);
    }
  }
}

// ---------------- final: out = x2 + ffn + Sinkhorn-mix(x) ----------------
__global__ __launch_bounds__(256) void final_kernel(const float* __restrict__ x,
                                                    const float* __restrict__ x2,
                                                    const float* __restrict__ ffn,
                                                    const float* __restrict__ H,
                                                    const float* __restrict__ g,
                                                    float* __restrict__ out) {
  const int row = blockIdx.x;
  const int tid = threadIdx.x;
  const int b = row >> 11;
  __shared__ float xs[DD];
  __shared__ float Wmn[64];
  const float* xr = x + (size_t)row * DD;
  *(f32x4*)&xs[tid * 8] = *(const f32x4*)&xr[tid * 8];
  *(f32x4*)&xs[tid * 8 + 4] = *(const f32x4*)&xr[tid * 8 + 4];
  if (tid < 64) Wmn[tid] = H[tid] * g[b * 8 + (tid & 7)];
  __syncthreads();
  const int mm = tid >> 5;
  const int dd0 = (tid * 8) & 255;
  const f32x4 a0 = *(const f32x4*)&x2[(size_t)row * DD + tid * 8];
  const f32x4 a1 = *(const f32x4*)&x2[(size_t)row * DD + tid * 8 + 4];
  const f32x4 f0 = *(const f32x4*)&ffn[(size_t)row * DD + tid * 8];
  const f32x4 f1 = *(const f32x4*)&ffn[(size_t)row * DD + tid * 8 + 4];
  f32x4 o0, o1;
#pragma unroll
  for (int e = 0; e < 8; ++e) {
    float acc = 0.f;
#pragma unroll
    for (int n = 0; n < 8; ++n) acc += Wmn[mm * 8 + n] * xs[n * 256 + dd0 + e];
    if (e < 4) o0[e] = a0[e] + f0[e] + acc;
    else       o1[e - 4] = a1[e - 4] + f1[e - 4] + acc;
  }
  *(f32x4*)&out[(size_t)row * DD + tid * 8] = o0;
  *(f32x4*)&out[(size_t)row * DD + tid * 8 + 4] = o1;
}

// ---------------- launcher ----------------
extern "C" void kernel_launch(void* const* d_in, const int* in_sizes, int n_in,
                              void* d_out, int out_size, void* d_ws, size_t ws_size,
                              hipStream_t stream) {
  const float* x      = (const float*)d_in[0];
  const float* gate_w = (const float*)d_in[3];
  const float* gate_b = (const float*)d_in[4];
  const float* phi    = (const float*)d_in[5];
  const float* ln1    = (const float*)d_in[6];
  const float* ln2    = (const float*)d_in[7];
  const float* inw    = (const float*)d_in[8];
  const float* inb    = (const float*)d_in[9];
  const float* outw   = (const float*)d_in[10];
  const float* outb   = (const float*)d_in[11];
  const float* w1     = (const float*)d_in[12];
  const float* b1     = (const float*)d_in[13];
  const float* w2     = (const float*)d_in[14];
  const float* b2     = (const float*)d_in[15];
  float* outp = (float*)d_out;
  char* ws = (char*)d_ws;

  // workspace layout (bytes)
  short* Wbf  = (short*)(ws + 0);                      // 33,554,432 (weight bf16 slot, reused)
  short* norm = (short*)(ws + 33554432ull);            // 16,777,216
  short* qkv  = (short*)(ws + 50331648ull);            // 50,331,648 (h bf16 overlays qkv+attn later)
  short* attn = (short*)(ws + 100663296ull);           // 16,777,216
  float* x2   = (float*)(ws + 117440512ull);           // 33,554,432
  float* ffn  = (float*)(ws + 150994944ull);           // 33,554,432
  float* part = (float*)(ws + 184549376ull);           // 131,072
  float* g    = (float*)(ws + 184680448ull);           // 64
  float* H    = (float*)(ws + 184680512ull);           // 256
  short* hbuf = qkv;                                   // [4096, 8192] bf16 overlay

  // stream-mixing prep
  mean_partial_kernel<<<dim3(8, 16), 256, 0, stream>>>(x, part);
  gates_kernel<<<16, 256, 0, stream>>>(part, gate_w, gate_b, g);
  sinkhorn_kernel<<<1, 64, 0, stream>>>(phi, H);

  // attention path
  rmsnorm_kernel<<<4096, 256, 0, stream>>>(x, ln1, norm);
  cvt_bf16_kernel<<<6144, 256, 0, stream>>>(inw, Wbf);
  gemm_nt<3><<<dim3(32, 48), 256, 0, stream>>>(norm, Wbf, inb, qkv, nullptr, 4096, 6144, 2048);
  flash_attn_kernel<<<dim3(32, 16, 2), 256, 0, stream>>>(qkv, attn);
  cvt_bf16_kernel<<<2048, 256, 0, stream>>>(outw, Wbf);
  gemm_nt<2><<<dim3(32, 16), 256, 0, stream>>>(attn, Wbf, outb, x2, x, 4096, 2048, 2048);

  // MLP path
  rmsnorm_kernel<<<4096, 256, 0, stream>>>(x2, ln2, norm);
  cvt_bf16_kernel<<<8192, 256, 0, stream>>>(w1, Wbf);
  gemm_nt<1><<<dim3(32, 64), 256, 0, stream>>>(norm, Wbf, b1, hbuf, nullptr, 4096, 8192, 2048);
  cvt_bf16_kernel<<<8192, 256, 0, stream>>>(w2, Wbf);
  gemm_nt<0><<<dim3(32, 16), 256, 0, stream>>>(hbuf, Wbf, b2, ffn, nullptr, 4096, 2048, 8192);

  // final fused add (+ Sinkhorn-gated stream mixing)
  final_kernel<<<4096, 256, 0, stream>>>(x, x2, ffn, H, g, outp);
}

// Round 5
// 1116.383 us; speedup vs baseline: 1.1286x; 1.1286x over previous
//
#include <hip/hip_runtime.h>
#include <hip/hip_bf16.h>

#define DD 2048
#define TT 2048
#define NHEAD 16
#define HDIM 128
#define QKVN 6144

typedef __attribute__((ext_vector_type(8))) short short8;
typedef __attribute__((ext_vector_type(4))) short s16x4;
typedef __attribute__((ext_vector_type(4))) float f32x4;

__device__ __forceinline__ short f2bf(float f) {
  __hip_bfloat16 h = __float2bfloat16(f);
  return *reinterpret_cast<short*>(&h);
}

__device__ __forceinline__ f32x4 mfma_bf16(short8 a, short8 b, f32x4 c) {
  return __builtin_amdgcn_mfma_f32_16x16x32_bf16(a, b, c, 0, 0, 0);
}

__device__ __forceinline__ float gelu_exact(float v) {
  return 0.5f * v * (1.0f + erff(v * 0.70710678118654752440f));
}

#define AS1(p) ((const __attribute__((address_space(1))) void*)(p))
#define AS3(p) ((__attribute__((address_space(3))) void*)(p))

// ---------------- fp32 -> bf16 convert (n multiple of 2048) ----------------
__global__ __launch_bounds__(256) void cvt_bf16_kernel(const float* __restrict__ in,
                                                       short* __restrict__ outp) {
  const size_t i = ((size_t)blockIdx.x * 256 + threadIdx.x) * 8;
  const f32x4 a = *(const f32x4*)&in[i];
  const f32x4 b = *(const f32x4*)&in[i + 4];
  short8 o;
#pragma unroll
  for (int e = 0; e < 4; ++e) { o[e] = f2bf(a[e]); o[e + 4] = f2bf(b[e]); }
  *(short8*)&outp[i] = o;
}

// ---------------- mean over T, partial sums ----------------
__global__ __launch_bounds__(256) void mean_partial_kernel(const float* __restrict__ x,
                                                           float* __restrict__ part) {
  const int d = blockIdx.x * 256 + threadIdx.x;
  const int y = blockIdx.y;
  const int b = y >> 3, tc = y & 7;
  const float* p = x + (size_t)b * TT * DD + (size_t)tc * 256 * DD + d;
  float s = 0.f;
#pragma unroll 4
  for (int t = 0; t < 256; ++t) s += p[(size_t)t * DD];
  part[(size_t)y * DD + d] = s;
}

// ---------------- gates ----------------
__global__ __launch_bounds__(256) void gates_kernel(const float* __restrict__ part,
                                                    const float* __restrict__ gw,
                                                    const float* __restrict__ gb,
                                                    float* __restrict__ g) {
  const int bm = blockIdx.x;
  const int b = bm >> 3, mm = bm & 7;
  const int j = 16 + mm;
  float acc = 0.f;
  for (int d = threadIdx.x; d < DD; d += 256) {
    float xv = 0.f;
#pragma unroll
    for (int tc = 0; tc < 8; ++tc) xv += part[(size_t)(b * 8 + tc) * DD + d];
    acc += xv * (1.f / TT) * gw[(size_t)j * DD + d];
  }
#pragma unroll
  for (int d = 1; d < 64; d <<= 1) acc += __shfl_xor(acc, d);
  __shared__ float ws4[4];
  if ((threadIdx.x & 63) == 0) ws4[threadIdx.x >> 6] = acc;
  __syncthreads();
  if (threadIdx.x == 0) {
    const float tot = ws4[0] + ws4[1] + ws4[2] + ws4[3] + gb[j];
    g[bm] = 1.f / (1.f + __expf(-tot));
  }
}

// ---------------- Sinkhorn-Knopp ----------------
__global__ void sinkhorn_kernel(const float* __restrict__ phi, float* __restrict__ H) {
  __shared__ float M[64];
  const int t = threadIdx.x;
  const int i = t >> 3, j = t & 7;
  M[t] = __expf(phi[t]);
  __syncthreads();
  for (int it = 0; it < 15; ++it) {
    float rs = 0.f;
#pragma unroll
    for (int jj = 0; jj < 8; ++jj) rs += M[i * 8 + jj];
    float v = M[t] / rs;
    __syncthreads(); M[t] = v; __syncthreads();
    float cs = 0.f;
#pragma unroll
    for (int ii = 0; ii < 8; ++ii) cs += M[ii * 8 + j];
    v = M[t] / cs;
    __syncthreads(); M[t] = v; __syncthreads();
  }
  H[t] = M[t];
}

// ---------------- RMSNorm fp32 -> bf16 ----------------
__global__ __launch_bounds__(256) void rmsnorm_kernel(const float* __restrict__ x,
                                                      const float* __restrict__ wt,
                                                      short* __restrict__ outp) {
  const int row = blockIdx.x;
  const int tid = threadIdx.x;
  const float* xr = x + (size_t)row * DD;
  const f32x4 v0 = *(const f32x4*)&xr[tid * 8];
  const f32x4 v1 = *(const f32x4*)&xr[tid * 8 + 4];
  float ss = 0.f;
#pragma unroll
  for (int e = 0; e < 4; ++e) ss += v0[e] * v0[e] + v1[e] * v1[e];
#pragma unroll
  for (int d = 1; d < 64; d <<= 1) ss += __shfl_xor(ss, d);
  __shared__ float wsum[4];
  if ((tid & 63) == 0) wsum[tid >> 6] = ss;
  __syncthreads();
  const float rstd = rsqrtf((wsum[0] + wsum[1] + wsum[2] + wsum[3]) * (1.f / DD) + 1e-6f);
  const f32x4 w0 = *(const f32x4*)&wt[tid * 8];
  const f32x4 w1 = *(const f32x4*)&wt[tid * 8 + 4];
  short8 ov;
#pragma unroll
  for (int e = 0; e < 4; ++e) {
    ov[e] = f2bf(v0[e] * rstd * w0[e]);
    ov[e + 4] = f2bf(v1[e] * rstd * w1[e]);
  }
  *(short8*)&outp[(size_t)row * DD + tid * 8] = ov;
}

// ---------------- NT bf16 GEMM (m97 structure: global_load_lds w16, pre-swizzled src) ---------
// EPI: 0 = fp32 out; 1 = GELU -> bf16; 2 = +resid -> fp32; 3 = bf16 out
template <int EPI>
__global__ __launch_bounds__(256) void gemm_nt(const short* __restrict__ A,
                                               const short* __restrict__ B,
                                               const float* __restrict__ bias,
                                               void* __restrict__ Cptr,
                                               const float* __restrict__ resid,
                                               int M, int N, int K) {
  __shared__ __align__(16) short As[128 * 64];
  __shared__ __align__(16) short Bs[128 * 64];
  const int tid = threadIdx.x;
  const int lane = tid & 63;
  const int wid = tid >> 6;
  const int bm = blockIdx.x * 128;
  const int bn = blockIdx.y * 128;
  const int wr = (wid >> 1) * 64;
  const int wc = (wid & 1) * 64;
  f32x4 acc[4][4] = {};

  // staging geometry: linear LDS slot (row, cd) holds global chunk cd ^ (row&7)
  const int srow_ = tid >> 3;                 // + p*32
  const int scs = (tid & 7) ^ (srow_ & 7);    // source chunk (XOR involution; p*32 ≡ 0 mod 8)

  for (int kb = 0; kb < K; kb += 64) {
    __syncthreads();
#pragma unroll
    for (int p = 0; p < 4; ++p) {
      const int row = p * 32 + srow_;
      const short* gA = &A[(size_t)(bm + row) * K + kb + (scs << 3)];
      const short* gB = &B[(size_t)(bn + row) * K + kb + (scs << 3)];
      __builtin_amdgcn_global_load_lds(AS1(gA), AS3(&As[p * 2048 + (tid & 192) * 8]), 16, 0, 0);
      __builtin_amdgcn_global_load_lds(AS1(gB), AS3(&Bs[p * 2048 + (tid & 192) * 8]), 16, 0, 0);
    }
    __syncthreads();
#pragma unroll
    for (int kk = 0; kk < 64; kk += 32) {
      short8 af[4], bfr[4];
#pragma unroll
      for (int i = 0; i < 4; ++i) {
        const int row = wr + i * 16 + (lane & 15);
        const int ch = ((kk >> 3) + (lane >> 4)) ^ (row & 7);
        af[i] = *(const short8*)&As[(row << 6) | (ch << 3)];
      }
#pragma unroll
      for (int j = 0; j < 4; ++j) {
        const int row = wc + j * 16 + (lane & 15);
        const int ch = ((kk >> 3) + (lane >> 4)) ^ (row & 7);
        bfr[j] = *(const short8*)&Bs[(row << 6) | (ch << 3)];
      }
#pragma unroll
      for (int i = 0; i < 4; ++i)
#pragma unroll
        for (int j = 0; j < 4; ++j)
          acc[i][j] = mfma_bf16(af[i], bfr[j], acc[i][j]);
    }
  }

  const int r0 = bm + wr + (lane >> 4) * 4;
  const int c0 = bn + wc + (lane & 15);
#pragma unroll
  for (int i = 0; i < 4; ++i) {
#pragma unroll
    for (int j = 0; j < 4; ++j) {
      const int col = c0 + j * 16;
      const float bv = bias[col];
#pragma unroll
      for (int r = 0; r < 4; ++r) {
        const int row = r0 + i * 16 + r;
        const float v = acc[i][j][r] + bv;
        if constexpr (EPI == 0) {
          ((float*)Cptr)[(size_t)row * N + col] = v;
        } else if constexpr (EPI == 1) {
          ((short*)Cptr)[(size_t)row * N + col] = f2bf(gelu_exact(v));
        } else if constexpr (EPI == 2) {
          ((float*)Cptr)[(size_t)row * N + col] = v + resid[(size_t)row * N + col];
        } else {
          ((short*)Cptr)[(size_t)row * N + col] = f2bf(v);
        }
      }
    }
  }
}

// ---------------- causal flash attention v3: swapped QK^T + tr_b16 V reads ----------------
// grid (32, 16, 2): 64 q-rows/block, 4 waves x 16 q each, KVBLK=64.
// tr_b16 semantics (m156 probe + m162 uniform-addr, reconciled): byte addr b ->
// 128B-aligned block b>>7 holds one [4][16] bf16 subtile; column = (b>>3)&15;
// elems j=0..3 are the subtile's rows (+16 shorts). Verified against m156's
// formula: b=8l -> block l>>4, col l&15 -> elems (l>>4)*64 + (l&15) + 16j.
__global__ __launch_bounds__(256) void flash_attn_kernel(const short* __restrict__ qkv,
                                                         short* __restrict__ attn) {
  const int tid = threadIdx.x;
  const int lane = tid & 63;
  const int w = tid >> 6;
  const int bx = blockIdx.x;
  const int qb = bx * 64;
  const int h = blockIdx.y;
  const int b = blockIdx.z;
  const int lr = lane & 15;
  const int lg = lane >> 4;

  __shared__ __align__(16) short Ks[64 * 128];   // [kv][d], chunk XOR-swizzled
  __shared__ __align__(16) short Vs[64 * 128];   // subtiled [kv/4][d/16][4][16]

  const size_t base = (size_t)b * (size_t)TT * QKVN;

  // Q fragment (B operand): col=q=lr, k-chunk kc*4+lg
  const int qrow = qb + w * 16 + lr;
  short8 qf[4];
#pragma unroll
  for (int kc = 0; kc < 4; ++kc)
    qf[kc] = *(const short8*)&qkv[base + (size_t)qrow * QKVN + h * HDIM + kc * 32 + lg * 8];

  // staging geometry: per p in 0..3: kv = p*16 + (tid>>4), chunk = tid&15
  const int skv0 = tid >> 4;
  const int sc_ = tid & 15;

  f32x4 o[8] = {};
  float m_run = -3e30f, Lpart = 0.f;
  const int ntiles = bx + 1;

  // prologue: stage tile 0
  {
    int4 rK[4], rV[4];
#pragma unroll
    for (int p = 0; p < 4; ++p) {
      const size_t grow = base + (size_t)(p * 16 + skv0) * QKVN + h * HDIM + sc_ * 8;
      rK[p] = *(const int4*)&qkv[grow + 2048];
      rV[p] = *(const int4*)&qkv[grow + 4096];
    }
#pragma unroll
    for (int p = 0; p < 4; ++p) {
      const int kv = p * 16 + skv0;
      *(int4*)&Ks[kv * 128 + ((sc_ ^ (skv0 & 7)) << 3)] = rK[p];
      *(int4*)&Vs[((kv >> 2) * 8 + (sc_ >> 1)) * 64 + (skv0 & 3) * 16 + (sc_ & 1) * 8] = rV[p];
    }
  }
  __syncthreads();

  const unsigned vsoff = (unsigned)(uintptr_t)((__attribute__((address_space(3))) short*)Vs);
  // base byte addr: block = lg*8 (kv>>2 = lg, ch=0), col = lr -> b = lg*1024 + lr*8
  const unsigned vbl = vsoff + (unsigned)(lg * 1024 + lr * 8);

  for (int t = 0; t < ntiles; ++t) {
    const bool masked = (t == ntiles - 1);
    int4 rK[4], rV[4];
    if (t + 1 < ntiles) {     // T14: issue next-tile loads before compute
      const int kv0n = (t + 1) * 64;
#pragma unroll
      for (int p = 0; p < 4; ++p) {
        const size_t grow = base + (size_t)(kv0n + p * 16 + skv0) * QKVN + h * HDIM + sc_ * 8;
        rK[p] = *(const int4*)&qkv[grow + 2048];
        rV[p] = *(const int4*)&qkv[grow + 4096];
      }
    }

    // ---- QK^T swapped: s[kb][r] = S[kv=kb*16+lg*4+r][q=lr]
    f32x4 s[4] = {};
#pragma unroll
    for (int kb = 0; kb < 4; ++kb) {
      if (masked && kb > w) continue;   // fully-masked kv block for this wave
#pragma unroll
      for (int kc = 0; kc < 4; ++kc) {
        const int row = kb * 16 + lr;
        const short8 kf = *(const short8*)&Ks[(row << 7) + ((((kc << 2) + lg) ^ (lr & 7)) << 3)];
        s[kb] = mfma_bf16(kf, qf[kc], s[kb]);
      }
    }

    // ---- online softmax per q=lr (4 lanes share a row: reduce over lg via xor 16,32)
    const float scl = 0.08838834764831845f;   // 1/sqrt(128)
    float sv[4][4];
    float pm = -3e30f;
#pragma unroll
    for (int kb = 0; kb < 4; ++kb)
#pragma unroll
      for (int r = 0; r < 4; ++r) {
        float v = s[kb][r] * scl;
        if (masked && (kb * 16 + lg * 4 + r > w * 16 + lr)) v = -3e30f;
        sv[kb][r] = v;
        pm = fmaxf(pm, v);
      }
    pm = fmaxf(pm, __shfl_xor(pm, 16));
    pm = fmaxf(pm, __shfl_xor(pm, 32));
    const float mn = fmaxf(m_run, pm);
    const float al = __expf(m_run - mn);
    m_run = mn;
    float ps = 0.f;
    short pb[16];
#pragma unroll
    for (int kb = 0; kb < 4; ++kb)
#pragma unroll
      for (int r = 0; r < 4; ++r) {
        const float p = __expf(sv[kb][r] - mn);
        ps += p;
        pb[kb * 4 + r] = f2bf(p);
      }
    Lpart = Lpart * al + ps;
    float alr[4];
#pragma unroll
    for (int r = 0; r < 4; ++r) alr[r] = __shfl(al, ((lane >> 4) << 2) + r);
#pragma unroll
    for (int ch = 0; ch < 8; ++ch)
#pragma unroll
      for (int r = 0; r < 4; ++r) o[ch][r] *= alr[r];

    // P lane-local for the PV A-operand: slot j <-> kv = k2*32 + (j>>2)*16 + lg*4 + (j&3)
    short8 pa[2];
#pragma unroll
    for (int k2 = 0; k2 < 2; ++k2)
#pragma unroll
      for (int j = 0; j < 8; ++j) pa[k2][j] = pb[k2 * 8 + j];

    // ---- PV via hardware transpose reads (V row-major-subtiled)
#pragma unroll
    for (int chp = 0; chp < 8; chp += 2) {
      s16x4 tv[8];
#pragma unroll
      for (int c2 = 0; c2 < 2; ++c2)
#pragma unroll
        for (int k2 = 0; k2 < 2; ++k2) {
          // block = k2*64 + s*32 + lg*8 + ch (s via offset:4096), col = lr
          const unsigned a0 = vbl + (unsigned)(k2 * 8192 + (chp + c2) * 128);
          const int ix = c2 * 4 + k2 * 2;
          asm volatile("ds_read_b64_tr_b16 %0, %2\n\t"
                       "ds_read_b64_tr_b16 %1, %2 offset:4096"
                       : "=&v"(tv[ix]), "=&v"(tv[ix + 1])
                       : "v"(a0));
        }
      asm volatile("s_waitcnt lgkmcnt(0)" ::: "memory");
      __builtin_amdgcn_sched_barrier(0);
#pragma unroll
      for (int c2 = 0; c2 < 2; ++c2)
#pragma unroll
        for (int k2 = 0; k2 < 2; ++k2) {
          const int ix = c2 * 4 + k2 * 2;
          short8 vf;
#pragma unroll
          for (int e = 0; e < 4; ++e) { vf[e] = tv[ix][e]; vf[e + 4] = tv[ix + 1][e]; }
          o[chp + c2] = mfma_bf16(pa[k2], vf, o[chp + c2]);
        }
    }

    if (t + 1 < ntiles) {
      __syncthreads();
#pragma unroll
      for (int p = 0; p < 4; ++p) {
        const int kv = p * 16 + skv0;
        *(int4*)&Ks[kv * 128 + ((sc_ ^ (skv0 & 7)) << 3)] = rK[p];
        *(int4*)&Vs[((kv >> 2) * 8 + (sc_ >> 1)) * 64 + (skv0 & 3) * 16 + (sc_ & 1) * 8] = rV[p];
      }
      __syncthreads();
    }
  }

  // ---- finalize: l per q, divide, store
  float Lq = Lpart;
  Lq += __shfl_xor(Lq, 16);
  Lq += __shfl_xor(Lq, 32);
  float inv[4];
#pragma unroll
  for (int r = 0; r < 4; ++r) inv[r] = 1.f / __shfl(Lq, ((lane >> 4) << 2) + r);
#pragma unroll
  for (int ch = 0; ch < 8; ++ch)
#pragma unroll
    for (int r = 0; r < 4; ++r) {
      const int row = qb + w * 16 + lg * 4 + r;
      attn[((size_t)b * TT + row) * DD + h * HDIM + ch * 16 + lr] = f2bf(o[ch][r] * inv[r]);
    }
}

// ---------------- final: out = x2 + ffn + Sinkhorn-mix(x) ----------------
__global__ __launch_bounds__(256) void final_kernel(const float* __restrict__ x,
                                                    const float* __restrict__ x2,
                                                    const float* __restrict__ ffn,
                                                    const float* __restrict__ H,
                                                    const float* __restrict__ g,
                                                    float* __restrict__ out) {
  const int row = blockIdx.x;
  const int tid = threadIdx.x;
  const int b = row >> 11;
  __shared__ float xs[DD];
  __shared__ float Wmn[64];
  const float* xr = x + (size_t)row * DD;
  *(f32x4*)&xs[tid * 8] = *(const f32x4*)&xr[tid * 8];
  *(f32x4*)&xs[tid * 8 + 4] = *(const f32x4*)&xr[tid * 8 + 4];
  if (tid < 64) Wmn[tid] = H[tid] * g[b * 8 + (tid & 7)];
  __syncthreads();
  const int mm = tid >> 5;
  const int dd0 = (tid * 8) & 255;
  const f32x4 a0 = *(const f32x4*)&x2[(size_t)row * DD + tid * 8];
  const f32x4 a1 = *(const f32x4*)&x2[(size_t)row * DD + tid * 8 + 4];
  const f32x4 f0 = *(const f32x4*)&ffn[(size_t)row * DD + tid * 8];
  const f32x4 f1 = *(const f32x4*)&ffn[(size_t)row * DD + tid * 8 + 4];
  f32x4 o0, o1;
#pragma unroll
  for (int e = 0; e < 8; ++e) {
    float acc = 0.f;
#pragma unroll
    for (int n = 0; n < 8; ++n) acc += Wmn[mm * 8 + n] * xs[n * 256 + dd0 + e];
    if (e < 4) o0[e] = a0[e] + f0[e] + acc;
    else       o1[e - 4] = a1[e - 4] + f1[e - 4] + acc;
  }
  *(f32x4*)&out[(size_t)row * DD + tid * 8] = o0;
  *(f32x4*)&out[(size_t)row * DD + tid * 8 + 4] = o1;
}

// ---------------- launcher ----------------
extern "C" void kernel_launch(void* const* d_in, const int* in_sizes, int n_in,
                              void* d_out, int out_size, void* d_ws, size_t ws_size,
                              hipStream_t stream) {
  const float* x      = (const float*)d_in[0];
  const float* gate_w = (const float*)d_in[3];
  const float* gate_b = (const float*)d_in[4];
  const float* phi    = (const float*)d_in[5];
  const float* ln1    = (const float*)d_in[6];
  const float* ln2    = (const float*)d_in[7];
  const float* inw    = (const float*)d_in[8];
  const float* inb    = (const float*)d_in[9];
  const float* outw   = (const float*)d_in[10];
  const float* outb   = (const float*)d_in[11];
  const float* w1     = (const float*)d_in[12];
  const float* b1     = (const float*)d_in[13];
  const float* w2     = (const float*)d_in[14];
  const float* b2     = (const float*)d_in[15];
  float* outp = (float*)d_out;
  char* ws = (char*)d_ws;

  short* Wbf  = (short*)(ws + 0);                      // 33.5 MB weight slot (reused)
  short* norm = (short*)(ws + 33554432ull);            // 16.8 MB
  short* qkv  = (short*)(ws + 50331648ull);            // 50.3 MB (hbuf overlays later)
  short* attn = (short*)(ws + 100663296ull);           // 16.8 MB
  float* x2   = (float*)(ws + 117440512ull);           // 33.5 MB
  float* ffn  = (float*)(ws + 150994944ull);           // 33.5 MB
  float* part = (float*)(ws + 184549376ull);
  float* g    = (float*)(ws + 184680448ull);
  float* H    = (float*)(ws + 184680512ull);
  short* hbuf = qkv;                                   // [4096, 8192] bf16 overlay

  mean_partial_kernel<<<dim3(8, 16), 256, 0, stream>>>(x, part);
  gates_kernel<<<16, 256, 0, stream>>>(part, gate_w, gate_b, g);
  sinkhorn_kernel<<<1, 64, 0, stream>>>(phi, H);

  rmsnorm_kernel<<<4096, 256, 0, stream>>>(x, ln1, norm);
  cvt_bf16_kernel<<<6144, 256, 0, stream>>>(inw, Wbf);
  gemm_nt<3><<<dim3(32, 48), 256, 0, stream>>>(norm, Wbf, inb, qkv, nullptr, 4096, 6144, 2048);
  flash_attn_kernel<<<dim3(32, 16, 2), 256, 0, stream>>>(qkv, attn);
  cvt_bf16_kernel<<<2048, 256, 0, stream>>>(outw, Wbf);
  gemm_nt<2><<<dim3(32, 16), 256, 0, stream>>>(attn, Wbf, outb, x2, x, 4096, 2048, 2048);

  rmsnorm_kernel<<<4096, 256, 0, stream>>>(x2, ln2, norm);
  cvt_bf16_kernel<<<8192, 256, 0, stream>>>(w1, Wbf);
  gemm_nt<1><<<dim3(32, 64), 256, 0, stream>>>(norm, Wbf, b1, hbuf, nullptr, 4096, 8192, 2048);
  cvt_bf16_kernel<<<8192, 256, 0, stream>>>(w2, Wbf);
  gemm_nt<0><<<dim3(32, 16), 256, 0, stream>>>(hbuf, Wbf, b2, ffn, nullptr, 4096, 2048, 8192);

  final_kernel<<<4096, 256, 0, stream>>>(x, x2, ffn, H, g, outp);
}